// Round 1
// baseline (2262.512 us; speedup 1.0000x reference)
//
#include <hip/hip_runtime.h>
#include <math.h>

#define TBn 16
#define Lpx 3136
#define CHW 301056      // 96*3136
#define SZn 4816896     // 16*96*3136
#define PRJ 1605632     // 16*32*3136

__device__ __forceinline__ float siluf_(float z){ return z / (1.f + expf(-z)); }
__device__ __forceinline__ float softplusf_(float z){ return fmaxf(z,0.f) + log1pf(expf(-fabsf(z))); }

// ---------------- per-pixel channel matmul: out[n,co,p] = sum_ci W[co,ci]*in[n,ci,p] (+bias) ----------------
__global__ __launch_bounds__(256) void k_matmul(const float* __restrict__ in, const float* __restrict__ Wm,
                                                const float* __restrict__ bias, float* __restrict__ out){
  int blk = blockIdx.x;
  int n = blk / 49, pt = blk % 49, p0 = pt * 64;
  __shared__ float lx[96*64];    // [ci][px]
  __shared__ float wl[96*33];    // [co][ci(32)+pad]
  int tid = threadIdx.x;
  const float* inb = in + (size_t)n*CHW;
  for (int i = tid; i < 96*64; i += 256){
    int ci = i >> 6, px = i & 63;
    lx[i] = inb[(size_t)ci*Lpx + p0 + px];
  }
  int px_t = tid & 15, co_t = tid >> 4;   // px base px_t*4, co base co_t*6
  float acc[6][4];
  #pragma unroll
  for (int j = 0; j < 6; ++j){
    float b = bias ? bias[co_t*6 + j] : 0.f;
    #pragma unroll
    for (int q = 0; q < 4; ++q) acc[j][q] = b;
  }
  for (int cc = 0; cc < 3; ++cc){
    __syncthreads();
    for (int i = tid; i < 96*32; i += 256){
      int co = i >> 5, ci = i & 31;
      wl[co*33 + ci] = Wm[co*96 + cc*32 + ci];
    }
    __syncthreads();
    for (int ci = 0; ci < 32; ++ci){
      float4 xv = *(const float4*)&lx[(cc*32 + ci)*64 + px_t*4];
      #pragma unroll
      for (int j = 0; j < 6; ++j){
        float w = wl[(co_t*6 + j)*33 + ci];
        acc[j][0] = fmaf(w, xv.x, acc[j][0]);
        acc[j][1] = fmaf(w, xv.y, acc[j][1]);
        acc[j][2] = fmaf(w, xv.z, acc[j][2]);
        acc[j][3] = fmaf(w, xv.w, acc[j][3]);
      }
    }
  }
  float* ob = out + (size_t)n*CHW + p0 + px_t*4;
  #pragma unroll
  for (int j = 0; j < 6; ++j){
    float4 v; v.x = acc[j][0]; v.y = acc[j][1]; v.z = acc[j][2]; v.w = acc[j][3];
    *(float4*)&ob[(size_t)(co_t*6 + j)*Lpx] = v;
  }
}

// ---------------- LIF over 16 steps (axis 0 of (16,96,56,56)) ----------------
__global__ __launch_bounds__(256) void k_lif1(const float* __restrict__ xp, float* __restrict__ sp){
  int i = blockIdx.x*256 + threadIdx.x;   // < CHW
  float v = 0.f;
  #pragma unroll
  for (int t = 0; t < 16; ++t){
    float z = xp[(size_t)t*CHW + i];
    v = 0.5f*(v + z);
    bool fire = (v >= 1.0f);
    sp[(size_t)t*CHW + i] = fire ? 1.f : 0.f;
    v = fire ? 0.f : v;
  }
}

// ---------------- dense 3x3 conv (96->96) + bias + silu ----------------
#define CIC 16
__global__ __launch_bounds__(256) void k_conv(const float* __restrict__ spk, const float* __restrict__ cw,
                                              const float* __restrict__ cb, float* __restrict__ out){
  int b = blockIdx.x, cog = blockIdx.y, ht = blockIdx.z;
  int co0 = cog*16, h0 = ht*4;
  int tid = threadIdx.x;
  int tx = tid & 63, ty = tid >> 6;
  __shared__ float ilds[CIC*6*58];
  __shared__ float wlds[CIC*9*16];
  float acc[16];
  #pragma unroll
  for (int j = 0; j < 16; ++j) acc[j] = 0.f;
  for (int cc = 0; cc < 6; ++cc){
    __syncthreads();
    for (int i = tid; i < CIC*6*58; i += 256){
      int ci = i / (6*58); int rem = i % (6*58);
      int hh = rem / 58, ww = rem % 58;
      int sh = h0 - 1 + hh, sw = ww - 1;
      float v = 0.f;
      if (sh >= 0 && sh < 56 && sw >= 0 && sw < 56)
        v = spk[(((size_t)b*96 + cc*CIC + ci)*56 + sh)*56 + sw];
      ilds[i] = v;
    }
    for (int i = tid; i < CIC*9*16; i += 256){
      int ci = i / 144; int rem = i % 144;
      int tap = rem / 16, co = rem % 16;
      wlds[i] = cw[(((size_t)(co0+co))*96 + cc*CIC + ci)*9 + tap];
    }
    __syncthreads();
    if (tx < 56){
      for (int ci = 0; ci < CIC; ++ci){
        #pragma unroll
        for (int tap = 0; tap < 9; ++tap){
          int dh = tap/3, dw = tap%3;
          float xv = ilds[(ci*6 + ty + dh)*58 + tx + dw];
          const float4* wp4 = (const float4*)&wlds[(ci*9 + tap)*16];
          float4 w0 = wp4[0], w1 = wp4[1], w2 = wp4[2], w3 = wp4[3];
          acc[0]  = fmaf(xv, w0.x, acc[0]);  acc[1]  = fmaf(xv, w0.y, acc[1]);
          acc[2]  = fmaf(xv, w0.z, acc[2]);  acc[3]  = fmaf(xv, w0.w, acc[3]);
          acc[4]  = fmaf(xv, w1.x, acc[4]);  acc[5]  = fmaf(xv, w1.y, acc[5]);
          acc[6]  = fmaf(xv, w1.z, acc[6]);  acc[7]  = fmaf(xv, w1.w, acc[7]);
          acc[8]  = fmaf(xv, w2.x, acc[8]);  acc[9]  = fmaf(xv, w2.y, acc[9]);
          acc[10] = fmaf(xv, w2.z, acc[10]); acc[11] = fmaf(xv, w2.w, acc[11]);
          acc[12] = fmaf(xv, w3.x, acc[12]); acc[13] = fmaf(xv, w3.y, acc[13]);
          acc[14] = fmaf(xv, w3.z, acc[14]); acc[15] = fmaf(xv, w3.w, acc[15]);
        }
      }
    }
  }
  if (tx < 56){
    #pragma unroll
    for (int j = 0; j < 16; ++j){
      float z = acc[j] + cb[co0 + j];
      out[(((size_t)b*96 + co0 + j)*56 + h0 + ty)*56 + tx] = siluf_(z);
    }
  }
}

// ---------------- depthwise 3x3 + silu, writes row-major and transposed ----------------
__global__ __launch_bounds__(256) void k_dwconv(const float* __restrict__ xin, const float* __restrict__ dwW,
                                                float* __restrict__ out, float* __restrict__ outT){
  int bd = blockIdx.x;           // b*96+d
  int d = bd % 96;
  const float* ip = xin + (size_t)bd*Lpx;
  __shared__ float pl[Lpx];
  __shared__ float po[Lpx];
  int tid = threadIdx.x;
  for (int i = tid; i < Lpx; i += 256) pl[i] = ip[i];
  float w9[9];
  #pragma unroll
  for (int t = 0; t < 9; ++t) w9[t] = dwW[d*9 + t];
  __syncthreads();
  for (int i = tid; i < Lpx; i += 256){
    int h = i / 56, w = i % 56;
    float s = 0.f;
    #pragma unroll
    for (int tap = 0; tap < 9; ++tap){
      int hh = h + tap/3 - 1, ww = w + tap%3 - 1;
      if (hh >= 0 && hh < 56 && ww >= 0 && ww < 56) s = fmaf(pl[hh*56 + ww], w9[tap], s);
    }
    po[i] = siluf_(s);
  }
  __syncthreads();
  float* op  = out  + (size_t)bd*Lpx;
  float* otp = outT + (size_t)bd*Lpx;
  for (int i = tid; i < Lpx; i += 256){
    op[i] = po[i];
    otp[i] = po[(i % 56)*56 + i/56];   // outT[w*56+h] = val(h,w)
  }
}

// ---------------- per-pixel 96->(4k x 8r) projections, row-major and transposed ----------------
__global__ __launch_bounds__(256) void k_proj(const float* __restrict__ xss, const float* __restrict__ xpw,
                                              float* __restrict__ PROJ, float* __restrict__ PROJT){
  int b = blockIdx.x / 56, h = blockIdx.x % 56;
  __shared__ float lx[96*56];    // [d][w]
  int tid = threadIdx.x;
  const float* xb = xss + (size_t)b*CHW + h*56;
  for (int i = tid; i < 96*56; i += 256){
    int d = i / 56, w = i % 56;
    lx[i] = xb[(size_t)d*Lpx + w];
  }
  __syncthreads();
  for (int o = tid; o < 32*56; o += 256){
    int w = o % 56, kr = o / 56;
    const float* wp = xpw + kr*96;
    float s = 0.f;
    for (int d = 0; d < 96; ++d) s = fmaf(lx[d*56 + w], wp[d], s);
    size_t base = ((size_t)b*32 + kr)*Lpx;
    PROJ[base + h*56 + w] = s;
    PROJT[base + w*56 + h] = s;
  }
}

// ---------------- bidirectional selective-scan: one wave per (b,d), dirs klo and klo+2 ----------------
__global__ __launch_bounds__(64) void k_scan(const float* __restrict__ xp, const float* __restrict__ PROJ,
                                             const float* __restrict__ dtw_all, const float* __restrict__ dtb_all,
                                             const float* __restrict__ Alog, const float* __restrict__ Dall,
                                             float* __restrict__ yout, int klo){
  int bd = blockIdx.x; int b = bd / 96, d = bd % 96;
  int kA = klo, kB = klo + 2;
  float dwA[6], dwB[6];
  #pragma unroll
  for (int r = 0; r < 6; ++r){ dwA[r] = dtw_all[(kA*96 + d)*6 + r]; dwB[r] = dtw_all[(kB*96 + d)*6 + r]; }
  float biA = dtb_all[kA*96 + d], biB = dtb_all[kB*96 + d];
  float AA = -expf(Alog[kA*96 + d]), AB = -expf(Alog[kB*96 + d]);
  float DA = Dall[kA*96 + d], DB = Dall[kB*96 + d];
  const float* pA = PROJ + ((size_t)b*32 + kA*8)*Lpx;
  const float* pB = PROJ + ((size_t)b*32 + kB*8)*Lpx;
  const float* xv = xp + (size_t)bd*Lpx;
  float* yo = yout + (size_t)bd*Lpx;
  int lane = threadIdx.x;
  int base = lane * 49;

  // pass 1: per-lane affine aggregates (forward for kA, reverse for kB)
  float aF = 1.f, bF = 0.f, aR = 1.f, bR = 0.f;
  for (int j = 0; j < 49; ++j){
    int p = base + j;
    float x_ = xv[p];
    float zA = biA;
    #pragma unroll
    for (int r = 0; r < 6; ++r) zA = fmaf(dwA[r], pA[(size_t)r*Lpx + p], zA);
    float dtA = softplusf_(zA);
    float daA = expf(dtA * AA);
    float dbA = dtA * pA[(size_t)6*Lpx + p] * x_;
    bF = fmaf(bF, daA, dbA); aF *= daA;
    float zB = biB;
    #pragma unroll
    for (int r = 0; r < 6; ++r) zB = fmaf(dwB[r], pB[(size_t)r*Lpx + p], zB);
    float dtB = softplusf_(zB);
    float daB = expf(dtB * AB);
    float dbB = dtB * pB[(size_t)6*Lpx + p] * x_;
    bR = fmaf(aR, dbB, bR); aR *= daB;    // prepend (element applied first in reverse time)
  }
  // wave inclusive scans of affine pairs
  float a = aF, bb = bF;
  #pragma unroll
  for (int off = 1; off < 64; off <<= 1){
    float ap = __shfl_up(a, off), bp = __shfl_up(bb, off);
    if (lane >= off){ bb = fmaf(a, bp, bb); a *= ap; }
  }
  float hin0 = __shfl_up(bb, 1); if (lane == 0) hin0 = 0.f;
  a = aR; bb = bR;
  #pragma unroll
  for (int off = 1; off < 64; off <<= 1){
    float ap = __shfl_down(a, off), bp = __shfl_down(bb, off);
    if (lane + off < 64){ bb = fmaf(a, bp, bb); a *= ap; }
  }
  float hin2 = __shfl_down(bb, 1); if (lane == 63) hin2 = 0.f;

  // pass 2a: forward kA, write ya = CsA*h + (DA+DB)*x
  float h = hin0;
  for (int j = 0; j < 49; ++j){
    int p = base + j;
    float x_ = xv[p];
    float zA = biA;
    #pragma unroll
    for (int r = 0; r < 6; ++r) zA = fmaf(dwA[r], pA[(size_t)r*Lpx + p], zA);
    float dtA = softplusf_(zA);
    float daA = expf(dtA * AA);
    float dbA = dtA * pA[(size_t)6*Lpx + p] * x_;
    h = fmaf(daA, h, dbA);
    yo[p] = fmaf(pA[(size_t)7*Lpx + p], h, (DA + DB) * x_);
  }
  // pass 2b: backward kB, accumulate CsB*h
  h = hin2;
  for (int j = 48; j >= 0; --j){
    int p = base + j;
    float x_ = xv[p];
    float zB = biB;
    #pragma unroll
    for (int r = 0; r < 6; ++r) zB = fmaf(dwB[r], pB[(size_t)r*Lpx + p], zB);
    float dtB = softplusf_(zB);
    float daB = expf(dtB * AB);
    float dbB = dtB * pB[(size_t)6*Lpx + p] * x_;
    h = fmaf(daB, h, dbB);
    yo[p] += pB[(size_t)7*Lpx + p] * h;
  }
}

// ---------------- 56x56 plane transpose (col-major -> row-major pixel layout) ----------------
__global__ __launch_bounds__(256) void k_transp(const float* __restrict__ in, float* __restrict__ out){
  int bd = blockIdx.x;
  __shared__ float t[Lpx];
  const float* ip = in + (size_t)bd*Lpx;
  float* op = out + (size_t)bd*Lpx;
  int tid = threadIdx.x;
  for (int i = tid; i < Lpx; i += 256) t[i] = ip[i];
  __syncthreads();
  for (int i = tid; i < Lpx; i += 256) op[i] = t[(i % 56)*56 + i/56];
}

// ---------------- combine ya+ybT, LayerNorm over channels ----------------
__global__ __launch_bounds__(256) void k_ln(const float* __restrict__ ya, const float* __restrict__ yb,
                                            const float* __restrict__ g, const float* __restrict__ be,
                                            float* __restrict__ out){
  int i = blockIdx.x*256 + threadIdx.x;    // b*L + p
  int b = i / Lpx, p = i % Lpx;
  const float* ap = ya + (size_t)b*CHW + p;
  const float* bp = yb + (size_t)b*CHW + p;
  float s = 0.f;
  for (int d = 0; d < 96; ++d) s += ap[(size_t)d*Lpx] + bp[(size_t)d*Lpx];
  float mu = s * (1.f/96.f);
  float ss = 0.f;
  for (int d = 0; d < 96; ++d){
    float v = ap[(size_t)d*Lpx] + bp[(size_t)d*Lpx] - mu;
    ss = fmaf(v, v, ss);
  }
  float rs = 1.f / sqrtf(ss * (1.f/96.f) + 1e-5f);
  float* op = out + (size_t)b*CHW + p;
  for (int d = 0; d < 96; ++d){
    float v = ap[(size_t)d*Lpx] + bp[(size_t)d*Lpx];
    op[(size_t)d*Lpx] = (v - mu) * rs * g[d] + be[d];
  }
}

// ---------------- LIF over T=4 + multiply with original x ----------------
__global__ __launch_bounds__(256) void k_lif2(const float* __restrict__ yo, const float* __restrict__ x0,
                                              float* __restrict__ out){
  const int stride = 1204224;   // B*C*L
  int i = blockIdx.x*256 + threadIdx.x;
  float v = 0.f;
  #pragma unroll
  for (int t = 0; t < 4; ++t){
    float z = yo[(size_t)t*stride + i];
    v = 0.5f*(v + z);
    bool fire = (v >= 1.0f);
    out[(size_t)t*stride + i] = fire ? x0[(size_t)t*stride + i] : 0.f;
    v = fire ? 0.f : v;
  }
}

extern "C" void kernel_launch(void* const* d_in, const int* in_sizes, int n_in,
                              void* d_out, int out_size, void* d_ws, size_t ws_size,
                              hipStream_t stream) {
  const float* x    = (const float*)d_in[0];
  const float* ipw  = (const float*)d_in[1];
  const float* ipb  = (const float*)d_in[2];
  const float* cw   = (const float*)d_in[3];
  const float* cb   = (const float*)d_in[4];
  const float* siw  = (const float*)d_in[5];
  const float* scw  = (const float*)d_in[6];
  const float* xpw  = (const float*)d_in[7];
  const float* dtw  = (const float*)d_in[8];
  const float* dtb  = (const float*)d_in[9];
  const float* alog = (const float*)d_in[10];
  const float* dsv  = (const float*)d_in[11];
  const float* lng  = (const float*)d_in[12];
  const float* lnb  = (const float*)d_in[13];
  const float* opw  = (const float*)d_in[14];

  float* s1 = (float*)d_ws;
  float* s2 = s1 + SZn;
  float* s3 = s2 + SZn;
  float* s4 = s3 + SZn;
  float* pr  = s4 + SZn;
  float* prT = pr + PRJ;

  // 1) in_proj (per-pixel 96x96) -> xp in s1
  k_matmul<<<784, 256, 0, stream>>>(x, ipw, ipb, s1);
  // 2) LIF over 16 steps -> spikes in s2
  k_lif1<<<1176, 256, 0, stream>>>(s1, s2);
  // 3) dense 3x3 conv + bias + silu -> xc in s1
  k_conv<<<dim3(16, 6, 14), 256, 0, stream>>>(s2, cw, cb, s1);
  // 4) ssm_in matmul -> s2
  k_matmul<<<784, 256, 0, stream>>>(s1, siw, nullptr, s2);
  // 5) depthwise conv + silu -> xss in s1, transposed copy in s3
  k_dwconv<<<1536, 256, 0, stream>>>(s2, scw, s1, s3);
  // 6) projections (pixel-indexed, both layouts)
  k_proj<<<896, 256, 0, stream>>>(s1, xpw, pr, prT);
  // 7) scan dirs 0&2 -> ya in s2
  k_scan<<<1536, 64, 0, stream>>>(s1, pr, dtw, dtb, alog, dsv, s2, 0);
  // 8) scan dirs 1&3 (col-major) -> yb_cm in s4
  k_scan<<<1536, 64, 0, stream>>>(s3, prT, dtw, dtb, alog, dsv, s4, 1);
  // 9) transpose yb_cm -> ybT in s1
  k_transp<<<1536, 256, 0, stream>>>(s4, s1);
  // 10) combine + LayerNorm -> yn in s3
  k_ln<<<196, 256, 0, stream>>>(s2, s1, lng, lnb, s3);
  // 11) out_proj -> yo in s4
  k_matmul<<<784, 256, 0, stream>>>(s3, opw, nullptr, s4);
  // 12) LIF over T=4, multiply with x -> d_out
  k_lif2<<<4704, 256, 0, stream>>>(s4, x, (float*)d_out);
}

// Round 2
// 992.363 us; speedup vs baseline: 2.2799x; 2.2799x over previous
//
#include <hip/hip_runtime.h>
#include <math.h>

#define TBn 16
#define Lpx 3136
#define CHW 301056      // 96*3136
#define SZn 4816896     // 16*96*3136
#define PRJ 1605632     // 16*32*3136
#define NPAD 3328       // 256*13

__device__ __forceinline__ float siluf_(float z){ return z / (1.f + expf(-z)); }
__device__ __forceinline__ float softplusf_(float z){ return fmaxf(z,0.f) + log1pf(expf(-fabsf(z))); }

// ---------------- per-pixel channel matmul: out[n,co,p] = sum_ci W[co,ci]*in[n,ci,p] (+bias) ----------------
__global__ __launch_bounds__(256) void k_matmul(const float* __restrict__ in, const float* __restrict__ Wm,
                                                const float* __restrict__ bias, float* __restrict__ out){
  int blk = blockIdx.x;
  int n = blk / 49, pt = blk % 49, p0 = pt * 64;
  __shared__ float lx[96*64];    // [ci][px]
  __shared__ float wl[96*33];    // [co][ci(32)+pad]
  int tid = threadIdx.x;
  const float* inb = in + (size_t)n*CHW;
  for (int i = tid; i < 96*64; i += 256){
    int ci = i >> 6, px = i & 63;
    lx[i] = inb[(size_t)ci*Lpx + p0 + px];
  }
  int px_t = tid & 15, co_t = tid >> 4;   // px base px_t*4, co base co_t*6
  float acc[6][4];
  #pragma unroll
  for (int j = 0; j < 6; ++j){
    float b = bias ? bias[co_t*6 + j] : 0.f;
    #pragma unroll
    for (int q = 0; q < 4; ++q) acc[j][q] = b;
  }
  for (int cc = 0; cc < 3; ++cc){
    __syncthreads();
    for (int i = tid; i < 96*32; i += 256){
      int co = i >> 5, ci = i & 31;
      wl[co*33 + ci] = Wm[co*96 + cc*32 + ci];
    }
    __syncthreads();
    for (int ci = 0; ci < 32; ++ci){
      float4 xv = *(const float4*)&lx[(cc*32 + ci)*64 + px_t*4];
      #pragma unroll
      for (int j = 0; j < 6; ++j){
        float w = wl[(co_t*6 + j)*33 + ci];
        acc[j][0] = fmaf(w, xv.x, acc[j][0]);
        acc[j][1] = fmaf(w, xv.y, acc[j][1]);
        acc[j][2] = fmaf(w, xv.z, acc[j][2]);
        acc[j][3] = fmaf(w, xv.w, acc[j][3]);
      }
    }
  }
  float* ob = out + (size_t)n*CHW + p0 + px_t*4;
  #pragma unroll
  for (int j = 0; j < 6; ++j){
    float4 v; v.x = acc[j][0]; v.y = acc[j][1]; v.z = acc[j][2]; v.w = acc[j][3];
    *(float4*)&ob[(size_t)(co_t*6 + j)*Lpx] = v;
  }
}

// ---------------- LIF over 16 steps (axis 0 of (16,96,56,56)) ----------------
__global__ __launch_bounds__(256) void k_lif1(const float* __restrict__ xp, float* __restrict__ sp){
  int i = blockIdx.x*256 + threadIdx.x;   // < CHW
  float v = 0.f;
  #pragma unroll
  for (int t = 0; t < 16; ++t){
    float z = xp[(size_t)t*CHW + i];
    v = 0.5f*(v + z);
    bool fire = (v >= 1.0f);
    sp[(size_t)t*CHW + i] = fire ? 1.f : 0.f;
    v = fire ? 0.f : v;
  }
}

// ---------------- dense 3x3 conv (96->96) + bias + silu ----------------
#define CIC 16
__global__ __launch_bounds__(256) void k_conv(const float* __restrict__ spk, const float* __restrict__ cw,
                                              const float* __restrict__ cb, float* __restrict__ out){
  int b = blockIdx.x, cog = blockIdx.y, ht = blockIdx.z;
  int co0 = cog*16, h0 = ht*4;
  int tid = threadIdx.x;
  int tx = tid & 63, ty = tid >> 6;
  __shared__ float ilds[CIC*6*58];
  __shared__ float wlds[CIC*9*16];
  float acc[16];
  #pragma unroll
  for (int j = 0; j < 16; ++j) acc[j] = 0.f;
  for (int cc = 0; cc < 6; ++cc){
    __syncthreads();
    for (int i = tid; i < CIC*6*58; i += 256){
      int ci = i / (6*58); int rem = i % (6*58);
      int hh = rem / 58, ww = rem % 58;
      int sh = h0 - 1 + hh, sw = ww - 1;
      float v = 0.f;
      if (sh >= 0 && sh < 56 && sw >= 0 && sw < 56)
        v = spk[(((size_t)b*96 + cc*CIC + ci)*56 + sh)*56 + sw];
      ilds[i] = v;
    }
    for (int i = tid; i < CIC*9*16; i += 256){
      int ci = i / 144; int rem = i % 144;
      int tap = rem / 16, co = rem % 16;
      wlds[i] = cw[(((size_t)(co0+co))*96 + cc*CIC + ci)*9 + tap];
    }
    __syncthreads();
    if (tx < 56){
      for (int ci = 0; ci < CIC; ++ci){
        #pragma unroll
        for (int tap = 0; tap < 9; ++tap){
          int dh = tap/3, dw = tap%3;
          float xv = ilds[(ci*6 + ty + dh)*58 + tx + dw];
          const float4* wp4 = (const float4*)&wlds[(ci*9 + tap)*16];
          float4 w0 = wp4[0], w1 = wp4[1], w2 = wp4[2], w3 = wp4[3];
          acc[0]  = fmaf(xv, w0.x, acc[0]);  acc[1]  = fmaf(xv, w0.y, acc[1]);
          acc[2]  = fmaf(xv, w0.z, acc[2]);  acc[3]  = fmaf(xv, w0.w, acc[3]);
          acc[4]  = fmaf(xv, w1.x, acc[4]);  acc[5]  = fmaf(xv, w1.y, acc[5]);
          acc[6]  = fmaf(xv, w1.z, acc[6]);  acc[7]  = fmaf(xv, w1.w, acc[7]);
          acc[8]  = fmaf(xv, w2.x, acc[8]);  acc[9]  = fmaf(xv, w2.y, acc[9]);
          acc[10] = fmaf(xv, w2.z, acc[10]); acc[11] = fmaf(xv, w2.w, acc[11]);
          acc[12] = fmaf(xv, w3.x, acc[12]); acc[13] = fmaf(xv, w3.y, acc[13]);
          acc[14] = fmaf(xv, w3.z, acc[14]); acc[15] = fmaf(xv, w3.w, acc[15]);
        }
      }
    }
  }
  if (tx < 56){
    #pragma unroll
    for (int j = 0; j < 16; ++j){
      float z = acc[j] + cb[co0 + j];
      out[(((size_t)b*96 + co0 + j)*56 + h0 + ty)*56 + tx] = siluf_(z);
    }
  }
}

// ---------------- depthwise 3x3 + silu, writes row-major and transposed ----------------
__global__ __launch_bounds__(256) void k_dwconv(const float* __restrict__ xin, const float* __restrict__ dwW,
                                                float* __restrict__ out, float* __restrict__ outT){
  int bd = blockIdx.x;           // b*96+d
  int d = bd % 96;
  const float* ip = xin + (size_t)bd*Lpx;
  __shared__ float pl[Lpx];
  __shared__ float po[Lpx];
  int tid = threadIdx.x;
  for (int i = tid; i < Lpx; i += 256) pl[i] = ip[i];
  float w9[9];
  #pragma unroll
  for (int t = 0; t < 9; ++t) w9[t] = dwW[d*9 + t];
  __syncthreads();
  for (int i = tid; i < Lpx; i += 256){
    int h = i / 56, w = i % 56;
    float s = 0.f;
    #pragma unroll
    for (int tap = 0; tap < 9; ++tap){
      int hh = h + tap/3 - 1, ww = w + tap%3 - 1;
      if (hh >= 0 && hh < 56 && ww >= 0 && ww < 56) s = fmaf(pl[hh*56 + ww], w9[tap], s);
    }
    po[i] = siluf_(s);
  }
  __syncthreads();
  float* op  = out  + (size_t)bd*Lpx;
  float* otp = outT + (size_t)bd*Lpx;
  for (int i = tid; i < Lpx; i += 256){
    op[i] = po[i];
    otp[i] = po[(i % 56)*56 + i/56];   // outT[w*56+h] = val(h,w)
  }
}

// ---------------- per-pixel 96->(4k x 8r) projections, row-major and transposed ----------------
__global__ __launch_bounds__(256) void k_proj(const float* __restrict__ xss, const float* __restrict__ xpw,
                                              float* __restrict__ PROJ, float* __restrict__ PROJT){
  int b = blockIdx.x / 56, h = blockIdx.x % 56;
  __shared__ float lx[96*56];    // [d][w]
  int tid = threadIdx.x;
  const float* xb = xss + (size_t)b*CHW + h*56;
  for (int i = tid; i < 96*56; i += 256){
    int d = i / 56, w = i % 56;
    lx[i] = xb[(size_t)d*Lpx + w];
  }
  __syncthreads();
  for (int o = tid; o < 32*56; o += 256){
    int w = o % 56, kr = o / 56;
    const float* wp = xpw + kr*96;
    float s = 0.f;
    for (int d = 0; d < 96; ++d) s = fmaf(lx[d*56 + w], wp[d], s);
    size_t base = ((size_t)b*32 + kr)*Lpx;
    PROJ[base + h*56 + w] = s;
    PROJT[base + w*56 + h] = s;
  }
}

// ---------------- block-parallel bidirectional selective scan ----------------
// one 256-thread block per (b,d); blockIdx.y = klo (0: dirs 0&2 row-major; 1: dirs 1&3 transposed)
// klo=1 writes its output transposed back to row-major (k_transp folded in).
__global__ __launch_bounds__(256) void k_scan2(const float* __restrict__ x_rm, const float* __restrict__ x_cm,
                                               const float* __restrict__ PROJ, const float* __restrict__ PROJT,
                                               const float* __restrict__ dtw_all, const float* __restrict__ dtb_all,
                                               const float* __restrict__ Alog, const float* __restrict__ Dall,
                                               float* __restrict__ out0, float* __restrict__ out1){
  int bd = blockIdx.x; int b = bd / 96, d = bd % 96;
  int klo = blockIdx.y;
  const float* xv = (klo == 0 ? x_rm : x_cm) + (size_t)bd*Lpx;
  const float* PR = (klo == 0 ? PROJ : PROJT);
  float* yo = (klo == 0 ? out0 : out1) + (size_t)bd*Lpx;
  int kA = klo, kB = klo + 2;

  float dwA[6], dwB[6];
  #pragma unroll
  for (int r = 0; r < 6; ++r){ dwA[r] = dtw_all[(kA*96 + d)*6 + r]; dwB[r] = dtw_all[(kB*96 + d)*6 + r]; }
  float biA = dtb_all[kA*96 + d], biB = dtb_all[kB*96 + d];
  float AA = -expf(Alog[kA*96 + d]), AB = -expf(Alog[kB*96 + d]);
  float Dsum = Dall[kA*96 + d] + Dall[kB*96 + d];
  const float* pA = PR + ((size_t)b*32 + kA*8)*Lpx;
  const float* pB = PR + ((size_t)b*32 + kB*8)*Lpx;

  __shared__ float xb[Lpx];
  __shared__ float u[NPAD];      // da -> local-inclusive a
  __shared__ float v[NPAD];      // db -> local-inclusive b -> h
  __shared__ float yacc[Lpx + 56];
  __shared__ float wag[8];       // wave aggregates: a[0..3], b[4..7]

  int tid = threadIdx.x;
  int lane = tid & 63, wv = tid >> 6;
  int base = tid * 13;

  for (int i = tid; i < Lpx; i += 256) xb[i] = xv[i];

  // ======== direction A (forward in p) ========
  for (int i = tid; i < Lpx; i += 256){
    float z = biA;
    #pragma unroll
    for (int r = 0; r < 6; ++r) z = fmaf(dwA[r], pA[(size_t)r*Lpx + i], z);
    float dt = softplusf_(z);
    u[i] = expf(dt * AA);
    v[i] = dt * pA[(size_t)6*Lpx + i] * xb[i];
  }
  for (int i = Lpx + tid; i < NPAD; i += 256){ u[i] = 1.f; v[i] = 0.f; }
  __syncthreads();

  {
    // local inclusive affine scan over this thread's 13 elements
    float a = 1.f, bb = 0.f;
    #pragma unroll
    for (int j = 0; j < 13; ++j){
      float da = u[base + j], db = v[base + j];
      bb = fmaf(da, bb, db);
      a *= da;
      u[base + j] = a; v[base + j] = bb;
    }
    // wave-inclusive scan of thread aggregates
    float aT = a, bT = bb;
    #pragma unroll
    for (int off = 1; off < 64; off <<= 1){
      float ap = __shfl_up(aT, off), bp = __shfl_up(bT, off);
      if (lane >= off){ bT = fmaf(aT, bp, bT); aT *= ap; }
    }
    if (lane == 63){ wag[wv] = aT; wag[4 + wv] = bT; }
    float a_ex = __shfl_up(aT, 1), b_ex = __shfl_up(bT, 1);
    if (lane == 0){ a_ex = 1.f; b_ex = 0.f; }
    __syncthreads();
    float hw = 0.f;
    for (int j = 0; j < wv; ++j) hw = fmaf(wag[j], hw, wag[4 + j]);
    float hin = fmaf(a_ex, hw, b_ex);
    #pragma unroll
    for (int j = 0; j < 13; ++j)
      v[base + j] = fmaf(u[base + j], hin, v[base + j]);    // h value
  }
  __syncthreads();
  for (int i = tid; i < Lpx; i += 256){
    float C = pA[(size_t)7*Lpx + i];
    yacc[i + i/56] = fmaf(C, v[i], Dsum * xb[i]);
  }
  __syncthreads();

  // ======== direction B (reverse in p) ========
  for (int i = tid; i < Lpx; i += 256){
    float z = biB;
    #pragma unroll
    for (int r = 0; r < 6; ++r) z = fmaf(dwB[r], pB[(size_t)r*Lpx + i], z);
    float dt = softplusf_(z);
    u[i] = expf(dt * AB);
    v[i] = dt * pB[(size_t)6*Lpx + i] * xb[i];
  }
  for (int i = Lpx + tid; i < NPAD; i += 256){ u[i] = 1.f; v[i] = 0.f; }
  __syncthreads();

  {
    // local suffix-inclusive scan (time = descending p)
    float a = 1.f, bb = 0.f;
    #pragma unroll
    for (int j = 12; j >= 0; --j){
      float da = u[base + j], db = v[base + j];
      bb = fmaf(da, bb, db);
      a *= da;
      u[base + j] = a; v[base + j] = bb;
    }
    // wave reverse-inclusive scan of thread aggregates
    float aT = a, bT = bb;
    #pragma unroll
    for (int off = 1; off < 64; off <<= 1){
      float ap = __shfl_down(aT, off), bp = __shfl_down(bT, off);
      if (lane + off < 64){ bT = fmaf(aT, bp, bT); aT *= ap; }
    }
    if (lane == 0){ wag[wv] = aT; wag[4 + wv] = bT; }
    float a_ex = __shfl_down(aT, 1), b_ex = __shfl_down(bT, 1);
    if (lane == 63){ a_ex = 1.f; b_ex = 0.f; }
    __syncthreads();
    float hw = 0.f;
    for (int j = 3; j > wv; --j) hw = fmaf(wag[j], hw, wag[4 + j]);
    float hin = fmaf(a_ex, hw, b_ex);
    #pragma unroll
    for (int j = 0; j < 13; ++j)
      v[base + j] = fmaf(u[base + j], hin, v[base + j]);    // h value
  }
  __syncthreads();
  for (int i = tid; i < Lpx; i += 256){
    float C = pB[(size_t)7*Lpx + i];
    yacc[i + i/56] = fmaf(C, v[i], yacc[i + i/56]);
  }
  __syncthreads();

  // ======== coalesced output ========
  if (klo == 0){
    for (int i = tid; i < Lpx; i += 256)
      yo[i] = yacc[i + i/56];
  } else {
    for (int i = tid; i < Lpx; i += 256){
      int q = (i % 56)*56 + i/56;             // transposed pixel
      yo[i] = yacc[q + q/56];                 // stride-57 LDS read: conflict-free
    }
  }
}

// ---------------- combine ya+yb, LayerNorm over channels ----------------
__global__ __launch_bounds__(256) void k_ln(const float* __restrict__ ya, const float* __restrict__ yb,
                                            const float* __restrict__ g, const float* __restrict__ be,
                                            float* __restrict__ out){
  int i = blockIdx.x*256 + threadIdx.x;    // b*L + p
  int b = i / Lpx, p = i % Lpx;
  const float* ap = ya + (size_t)b*CHW + p;
  const float* bp = yb + (size_t)b*CHW + p;
  float s = 0.f;
  for (int d = 0; d < 96; ++d) s += ap[(size_t)d*Lpx] + bp[(size_t)d*Lpx];
  float mu = s * (1.f/96.f);
  float ss = 0.f;
  for (int d = 0; d < 96; ++d){
    float v = ap[(size_t)d*Lpx] + bp[(size_t)d*Lpx] - mu;
    ss = fmaf(v, v, ss);
  }
  float rs = 1.f / sqrtf(ss * (1.f/96.f) + 1e-5f);
  float* op = out + (size_t)b*CHW + p;
  for (int d = 0; d < 96; ++d){
    float v = ap[(size_t)d*Lpx] + bp[(size_t)d*Lpx];
    op[(size_t)d*Lpx] = (v - mu) * rs * g[d] + be[d];
  }
}

// ---------------- LIF over T=4 + multiply with original x ----------------
__global__ __launch_bounds__(256) void k_lif2(const float* __restrict__ yo, const float* __restrict__ x0,
                                              float* __restrict__ out){
  const int stride = 1204224;   // B*C*L
  int i = blockIdx.x*256 + threadIdx.x;
  float v = 0.f;
  #pragma unroll
  for (int t = 0; t < 4; ++t){
    float z = yo[(size_t)t*stride + i];
    v = 0.5f*(v + z);
    bool fire = (v >= 1.0f);
    out[(size_t)t*stride + i] = fire ? x0[(size_t)t*stride + i] : 0.f;
    v = fire ? 0.f : v;
  }
}

extern "C" void kernel_launch(void* const* d_in, const int* in_sizes, int n_in,
                              void* d_out, int out_size, void* d_ws, size_t ws_size,
                              hipStream_t stream) {
  const float* x    = (const float*)d_in[0];
  const float* ipw  = (const float*)d_in[1];
  const float* ipb  = (const float*)d_in[2];
  const float* cw   = (const float*)d_in[3];
  const float* cb   = (const float*)d_in[4];
  const float* siw  = (const float*)d_in[5];
  const float* scw  = (const float*)d_in[6];
  const float* xpw  = (const float*)d_in[7];
  const float* dtw  = (const float*)d_in[8];
  const float* dtb  = (const float*)d_in[9];
  const float* alog = (const float*)d_in[10];
  const float* dsv  = (const float*)d_in[11];
  const float* lng  = (const float*)d_in[12];
  const float* lnb  = (const float*)d_in[13];
  const float* opw  = (const float*)d_in[14];

  float* s1 = (float*)d_ws;
  float* s2 = s1 + SZn;
  float* s3 = s2 + SZn;
  float* s4 = s3 + SZn;
  float* pr  = s4 + SZn;
  float* prT = pr + PRJ;

  // 1) in_proj (per-pixel 96x96) -> xp in s1
  k_matmul<<<784, 256, 0, stream>>>(x, ipw, ipb, s1);
  // 2) LIF over 16 steps -> spikes in s2
  k_lif1<<<1176, 256, 0, stream>>>(s1, s2);
  // 3) dense 3x3 conv + bias + silu -> xc in s1
  k_conv<<<dim3(16, 6, 14), 256, 0, stream>>>(s2, cw, cb, s1);
  // 4) ssm_in matmul -> s2
  k_matmul<<<784, 256, 0, stream>>>(s1, siw, nullptr, s2);
  // 5) depthwise conv + silu -> xss rm in s1, cm in s3
  k_dwconv<<<1536, 256, 0, stream>>>(s2, scw, s1, s3);
  // 6) projections (pixel-indexed, both layouts)
  k_proj<<<896, 256, 0, stream>>>(s1, xpw, pr, prT);
  // 7) both scan dir-pairs in one dispatch: ya -> s2, yb(row-major) -> s4
  k_scan2<<<dim3(1536, 2), 256, 0, stream>>>(s1, s3, pr, prT, dtw, dtb, alog, dsv, s2, s4);
  // 8) combine + LayerNorm -> s3
  k_ln<<<196, 256, 0, stream>>>(s2, s4, lng, lnb, s3);
  // 9) out_proj -> s2
  k_matmul<<<784, 256, 0, stream>>>(s3, opw, nullptr, s2);
  // 10) LIF over T=4, multiply with x -> d_out
  k_lif2<<<4704, 256, 0, stream>>>(s2, x, (float*)d_out);
}